// Round 3
// baseline (275.231 us; speedup 1.0000x reference)
//
#include <hip/hip_runtime.h>
#include <math.h>

#define T_STEPS 1024
#define BSZ     512
#define NDIM    256
#define ODIM    10
#define NCHUNK  8
#define CHUNK   128   // T_STEPS / NCHUNK

// ---------------- common DPP helpers ----------------
// DPP fetch with identity padding: lanes with invalid source (or masked off by
// RMASK) receive `ident` (old value), so affine compose is a no-op for them.
template<int CTRL, int RMASK>
__device__ __forceinline__ float dpp_fetch(float x, float ident) {
    return __int_as_float(__builtin_amdgcn_update_dpp(
        __float_as_int(ident), __float_as_int(x), CTRL, RMASK, 0xF, false));
}

// One affine-scan round: compose current map (Ac,Bc) after fetched earlier map.
#define SCAN_ROUND(CTRL, RMASK)                                   \
    {   const float Ap = dpp_fetch<CTRL, RMASK>(Ac, 1.0f);        \
        const float Bp = dpp_fetch<CTRL, RMASK>(Bc, 0.0f);        \
        Bc = fmaf(Ac, Bp, Bc);                                    \
        Ac = Ac * Ap; }

// fast reciprocal (fallback path): v_rcp_f32 + 1 Newton step
__device__ __forceinline__ float fast_rcp(float x) {
    float r = __builtin_amdgcn_rcpf(x);
    return fmaf(r, fmaf(-x, r, 1.0f), r);
}

// ---------------- coefficient table ----------------
// Per (t, m) with m = 4*lane + j, k = 255 - m (k descending in scan order):
//   a = dt/2, dt = 1/t
//   d  = 1/(1 + a(k+1))
//   al = (1 - ak) d           (S' = al*S + d*G)
//   e  = (1 - a(k+1)) d       (G' = e*G - r*S)
//   r  = a(2k+1) (1 + e)
// For m == 255 (the last element in scan order), d and al are pre-scaled by dt
// so the wave-final S equals Weff[o,t] directly (no per-step epilogue).
__global__ __launch_bounds__(256) void coef_kernel(float4* __restrict__ ctab) {
    const int t = blockIdx.x + 1;        // 1..1024
    const int m = threadIdx.x;           // 0..255
    const int k = 255 - m;
    const double a     = 0.5 / (double)t;
    const double denom = 1.0 + a * (double)(k + 1);
    double d  = 1.0 / denom;
    const double a21 = a * (double)(2 * k + 1);
    double al = 1.0 - a21 * d;           // (1 - a k)/denom
    const double e  = (1.0 - a * (double)(k + 1)) * d;
    const double r  = a21 * (1.0 + e);
    if (m == 255) {                      // fold dt into the final slot's map
        const double dt = 1.0 / (double)t;
        d *= dt; al *= dt;
    }
    ctab[(size_t)blockIdx.x * NDIM + m] =
        make_float4((float)d, (float)al, (float)e, (float)r);
}

// ---------------- Weff scan kernel (table path) ----------------
// Weff[t][o] = dt * B^T lhs_t^{-T} g_t, backward recurrence g_{t-1} = Ad_t^T g_t,
// g_T = mlp_w[o,:]. Scaled state G_k = q_k g_k. Per k descending:
//   S' = al*S + d*G ; G' = e*G - r*S ; Weff = dt * S_final.
// One wave per o; lane l slot j holds k = 255-(4l+j). The per-t inner solve is a
// 256-long affine scan: 4-slot in-lane compose + 6-round DPP wave scan.
#define WSTEP(CB, TT) do {                                                     \
    float be_[4], al_[4], e_[4], r_[4];                                        \
    _Pragma("unroll")                                                          \
    for (int j = 0; j < 4; ++j) {                                              \
        be_[j] = CB[j].x * G[j];                                               \
        al_[j] = CB[j].y; e_[j] = CB[j].z; r_[j] = CB[j].w;                    \
    }                                                                          \
    {   /* reload CB for step TT-4 (clamped); consumed 4 steps later */        \
        const int row_ = ((TT) > 4) ? ((TT) - 5) : 0;                          \
        const float4* rp_ = ctab + (size_t)row_ * NDIM + 4 * lane;             \
        _Pragma("unroll")                                                      \
        for (int j = 0; j < 4; ++j) CB[j] = rp_[j];                            \
    }                                                                          \
    float Ac = al_[0], Bc = be_[0];                                            \
    _Pragma("unroll")                                                          \
    for (int j = 1; j < 4; ++j) { Bc = fmaf(al_[j], Bc, be_[j]); Ac *= al_[j]; } \
    SCAN_ROUND(0x111, 0xF)   /* row_shr:1  */                                  \
    SCAN_ROUND(0x112, 0xF)   /* row_shr:2  */                                  \
    SCAN_ROUND(0x114, 0xF)   /* row_shr:4  */                                  \
    SCAN_ROUND(0x118, 0xF)   /* row_shr:8  */                                  \
    SCAN_ROUND(0x142, 0xA)   /* row_bcast15 -> rows 1,3 */                     \
    {   /* row_bcast31 -> rows 2,3 ; B-only (A unused afterwards) */           \
        const float Bp = dpp_fetch<0x143, 0xC>(Bc, 0.0f);                      \
        Bc = fmaf(Ac, Bp, Bc);                                                 \
    }                                                                          \
    float S = dpp_fetch<0x138, 0xF>(Bc, 0.0f);  /* wave_shr:1, lane0 -> 0 */   \
    _Pragma("unroll")                                                          \
    for (int j = 0; j < 4; ++j) {                                              \
        G[j] = fmaf(-r_[j], S, e_[j] * G[j]);                                  \
        S    = fmaf(al_[j], S, be_[j]);                                        \
    }                                                                          \
    if (lane == 63) weff[((TT) - 1) * ODIM + o] = S;                           \
} while (0)

__global__ __launch_bounds__(64) void weff_tab_kernel(const float4* __restrict__ ctab,
                                                      const float* __restrict__ mlp_w,
                                                      float* __restrict__ weff) {
    const int o    = blockIdx.x;   // 0..9
    const int lane = threadIdx.x;  // 0..63

    float G[4];
#pragma unroll
    for (int j = 0; j < 4; ++j) {
        const int k = 255 - (4 * lane + j);
        G[j] = sqrtf((float)(2 * k + 1)) * mlp_w[o * NDIM + k];
    }

    // 4-deep register ring of coefficient rows (prefetch distance ~3 steps)
    float4 cb0[4], cb1[4], cb2[4], cb3[4];
    {
        const float4* rp = ctab + (size_t)(T_STEPS - 1) * NDIM + 4 * lane;
#pragma unroll
        for (int j = 0; j < 4; ++j) cb0[j] = rp[j];
        rp -= NDIM;
#pragma unroll
        for (int j = 0; j < 4; ++j) cb1[j] = rp[j];
        rp -= NDIM;
#pragma unroll
        for (int j = 0; j < 4; ++j) cb2[j] = rp[j];
        rp -= NDIM;
#pragma unroll
        for (int j = 0; j < 4; ++j) cb3[j] = rp[j];
    }

    for (int t = T_STEPS; t >= 4; t -= 4) {
        WSTEP(cb0, t);
        WSTEP(cb1, t - 1);
        WSTEP(cb2, t - 2);
        WSTEP(cb3, t - 3);
    }
}

// ---------------- Weff scan kernel (inline fallback, no table) ----------------
__global__ __launch_bounds__(64) void weff_inline_kernel(const float* __restrict__ mlp_w,
                                                         float* __restrict__ weff) {
    const int o    = blockIdx.x;
    const int lane = threadIdx.x;

    float G[4], kp1[4], tk[4];
#pragma unroll
    for (int j = 0; j < 4; ++j) {
        const int k = 255 - (4 * lane + j);
        kp1[j] = (float)(k + 1);
        tk[j]  = (float)(2 * k + 1);
        G[j]   = sqrtf((float)(2 * k + 1)) * mlp_w[o * NDIM + k];
    }

    for (int t = T_STEPS; t >= 1; --t) {
        const float dt = fast_rcp((float)t);
        const float a  = 0.5f * dt;

        float d[4], a21[4], c2[4], al[4], be[4];
#pragma unroll
        for (int j = 0; j < 4; ++j) {
            const float denom = fmaf(a, kp1[j], 1.0f);
            d[j]   = fast_rcp(denom);
            a21[j] = a * tk[j];
            c2[j]  = fmaf(-a, kp1[j], 1.0f);
            al[j]  = fmaf(-a21[j], d[j], 1.0f);
            be[j]  = d[j] * G[j];
        }

        float Ac = al[0], Bc = be[0];
#pragma unroll
        for (int j = 1; j < 4; ++j) { Bc = fmaf(al[j], Bc, be[j]); Ac *= al[j]; }

        SCAN_ROUND(0x111, 0xF)
        SCAN_ROUND(0x112, 0xF)
        SCAN_ROUND(0x114, 0xF)
        SCAN_ROUND(0x118, 0xF)
        SCAN_ROUND(0x142, 0xA)
        SCAN_ROUND(0x143, 0xC)

        float S = dpp_fetch<0x138, 0xF>(Bc, 0.0f);
#pragma unroll
        for (int j = 0; j < 4; ++j) {
            const float w = a21[j] * S;
            const float u = fmaf(-d[j], w, be[j]);
            G[j] = fmaf(c2[j], u, -w);
            S    = fmaf(al[j], S, be[j]);
        }

        if (lane == 63) weff[(t - 1) * ODIM + o] = dt * S;
    }
}

// ---------------- contraction: out[b,o] = bias + sum_t f[t,b] weff[t,o] -------
__global__ __launch_bounds__(128) void partial_kernel(const float* __restrict__ f,
                                                      const float* __restrict__ weff,
                                                      float* __restrict__ part) {
    __shared__ float wsm[CHUNK * ODIM];
    const int tid = threadIdx.x;
    const int b   = blockIdx.x * 128 + tid;
    const int tc  = blockIdx.y;
    const int t0  = tc * CHUNK;

    for (int i = tid; i < CHUNK * ODIM; i += 128)
        wsm[i] = weff[t0 * ODIM + i];
    __syncthreads();

    float acc[ODIM];
#pragma unroll
    for (int o = 0; o < ODIM; ++o) acc[o] = 0.0f;

    for (int tt = 0; tt < CHUNK; ++tt) {
        const float fv = f[(t0 + tt) * BSZ + b];   // coalesced over b
#pragma unroll
        for (int o = 0; o < ODIM; ++o)
            acc[o] = fmaf(fv, wsm[tt * ODIM + o], acc[o]);
    }

#pragma unroll
    for (int o = 0; o < ODIM; ++o)
        part[(tc * BSZ + b) * ODIM + o] = acc[o];
}

__global__ __launch_bounds__(256) void reduce_kernel(const float* __restrict__ part,
                                                     const float* __restrict__ mlp_b,
                                                     float* __restrict__ out) {
    const int i = blockIdx.x * 256 + threadIdx.x;
    if (i >= BSZ * ODIM) return;
    const int o = i % ODIM;
    float s = mlp_b[o];
#pragma unroll
    for (int c = 0; c < NCHUNK; ++c) s += part[c * BSZ * ODIM + i];
    out[i] = s;
}

extern "C" void kernel_launch(void* const* d_in, const int* in_sizes, int n_in,
                              void* d_out, int out_size, void* d_ws, size_t ws_size,
                              hipStream_t stream) {
    const float* inputs = (const float*)d_in[0];  // [T=1024, B=512, 1]
    const float* mlp_w  = (const float*)d_in[1];  // [10, 256]
    const float* mlp_b  = (const float*)d_in[2];  // [10]
    float* out = (float*)d_out;                   // [512, 10]

    const size_t tab_bytes  = (size_t)T_STEPS * NDIM * sizeof(float4); // 4 MB
    const size_t weff_elems = (size_t)T_STEPS * ODIM;
    const size_t part_elems = (size_t)NCHUNK * BSZ * ODIM;
    const size_t small_bytes = (weff_elems + part_elems) * sizeof(float);

    if (ws_size >= tab_bytes + small_bytes) {
        float4* ctab = (float4*)d_ws;
        float*  weff = (float*)((char*)d_ws + tab_bytes);
        float*  part = weff + weff_elems;
        coef_kernel<<<T_STEPS, 256, 0, stream>>>(ctab);
        weff_tab_kernel<<<ODIM, 64, 0, stream>>>(ctab, mlp_w, weff);
        partial_kernel<<<dim3(BSZ / 128, NCHUNK), 128, 0, stream>>>(inputs, weff, part);
        reduce_kernel<<<(BSZ * ODIM + 255) / 256, 256, 0, stream>>>(part, mlp_b, out);
    } else {
        float* weff = (float*)d_ws;
        float* part = weff + weff_elems;
        weff_inline_kernel<<<ODIM, 64, 0, stream>>>(mlp_w, weff);
        partial_kernel<<<dim3(BSZ / 128, NCHUNK), 128, 0, stream>>>(inputs, weff, part);
        reduce_kernel<<<(BSZ * ODIM + 255) / 256, 256, 0, stream>>>(part, mlp_b, out);
    }
}

// Round 4
// 265.585 us; speedup vs baseline: 1.0363x; 1.0363x over previous
//
#include <hip/hip_runtime.h>
#include <math.h>

#define T_STEPS 1024
#define BSZ     512
#define NDIM    256
#define ODIM    10
#define NCHUNK  8
#define CHUNK   128   // T_STEPS / NCHUNK

// ---------------- common DPP helpers ----------------
// DPP fetch with identity padding: lanes with invalid source (or masked off by
// RMASK) receive `ident` (old value), so affine compose is a no-op for them.
template<int CTRL, int RMASK>
__device__ __forceinline__ float dpp_fetch(float x, float ident) {
    return __int_as_float(__builtin_amdgcn_update_dpp(
        __float_as_int(ident), __float_as_int(x), CTRL, RMASK, 0xF, false));
}

// One affine-scan round: compose current map (Ac,Bc) after fetched earlier map.
#define SCAN_ROUND(CTRL, RMASK)                                   \
    {   const float Ap = dpp_fetch<CTRL, RMASK>(Ac, 1.0f);        \
        const float Bp = dpp_fetch<CTRL, RMASK>(Bc, 0.0f);        \
        Bc = fmaf(Ac, Bp, Bc);                                    \
        Ac = Ac * Ap; }

// fast reciprocal (fallback path): v_rcp_f32 + 1 Newton step
__device__ __forceinline__ float fast_rcp(float x) {
    float r = __builtin_amdgcn_rcpf(x);
    return fmaf(r, fmaf(-x, r, 1.0f), r);
}

// ---------------- coefficient table ----------------
// Per (t, m) with m = 4*lane + j, k = 255 - m (k descending in scan order):
//   a = dt/2, dt = 1/t
//   d  = 1/(1 + a(k+1))
//   al = (1 - ak) d           (S' = al*S + d*G)
//   e  = (1 - a(k+1)) d       (G' = e*G - r*S)
//   r  = a(2k+1) (1 + e)
// For m == 255 (the last element in scan order), d and al are pre-scaled by dt
// so the wave-final S equals Weff[o,t] directly (no per-step epilogue).
__global__ __launch_bounds__(256) void coef_kernel(float4* __restrict__ ctab) {
    const int t = blockIdx.x + 1;        // 1..1024
    const int m = threadIdx.x;           // 0..255
    const int k = 255 - m;
    const double a     = 0.5 / (double)t;
    const double denom = 1.0 + a * (double)(k + 1);
    double d  = 1.0 / denom;
    const double a21 = a * (double)(2 * k + 1);
    double al = 1.0 - a21 * d;           // (1 - a k)/denom
    const double e  = (1.0 - a * (double)(k + 1)) * d;
    const double r  = a21 * (1.0 + e);
    if (m == 255) {                      // fold dt into the final slot's map
        const double dt = 1.0 / (double)t;
        d *= dt; al *= dt;
    }
    ctab[(size_t)blockIdx.x * NDIM + m] =
        make_float4((float)d, (float)al, (float)e, (float)r);
}

// ---------------- Weff scan kernel (table path) ----------------
// Weff[t][o] = dt * B^T lhs_t^{-T} g_t, backward recurrence g_{t-1} = Ad_t^T g_t,
// g_T = mlp_w[o,:]. Scaled state G_k = q_k g_k. Per k descending:
//   S' = al*S + d*G ; G' = e*G - r*S ; Weff = dt * S_final.
// One wave per o; lane l slot j holds k = 255-(4l+j). The per-t inner solve is a
// 256-long affine scan: 4-slot in-lane compose + 6-round DPP wave scan.
// Register ring depth 8: row for step TT-8 is loaded while step TT computes,
// giving a ~8*T_step (>1000 cy) prefetch horizon to hide L3/HBM latency.
#define WSTEP(CB, TT) do {                                                     \
    float be_[4], al_[4], e_[4], r_[4];                                        \
    _Pragma("unroll")                                                          \
    for (int j = 0; j < 4; ++j) {                                              \
        be_[j] = CB[j].x * G[j];                                               \
        al_[j] = CB[j].y; e_[j] = CB[j].z; r_[j] = CB[j].w;                    \
    }                                                                          \
    {   /* reload CB with row for step TT-8 (clamped); consumed 8 steps later */\
        const int row_ = ((TT) > 8) ? ((TT) - 9) : 0;                          \
        const float4* rp_ = ctab + (size_t)row_ * NDIM + 4 * lane;             \
        _Pragma("unroll")                                                      \
        for (int j = 0; j < 4; ++j) CB[j] = rp_[j];                            \
    }                                                                          \
    float Ac = al_[0], Bc = be_[0];                                            \
    _Pragma("unroll")                                                          \
    for (int j = 1; j < 4; ++j) { Bc = fmaf(al_[j], Bc, be_[j]); Ac *= al_[j]; } \
    SCAN_ROUND(0x111, 0xF)   /* row_shr:1  */                                  \
    SCAN_ROUND(0x112, 0xF)   /* row_shr:2  */                                  \
    SCAN_ROUND(0x114, 0xF)   /* row_shr:4  */                                  \
    SCAN_ROUND(0x118, 0xF)   /* row_shr:8  */                                  \
    SCAN_ROUND(0x142, 0xA)   /* row_bcast15 -> rows 1,3 */                     \
    {   /* row_bcast31 -> rows 2,3 ; B-only (A unused afterwards) */           \
        const float Bp = dpp_fetch<0x143, 0xC>(Bc, 0.0f);                      \
        Bc = fmaf(Ac, Bp, Bc);                                                 \
    }                                                                          \
    float S = dpp_fetch<0x138, 0xF>(Bc, 0.0f);  /* wave_shr:1, lane0 -> 0 */   \
    _Pragma("unroll")                                                          \
    for (int j = 0; j < 4; ++j) {                                              \
        G[j] = fmaf(-r_[j], S, e_[j] * G[j]);                                  \
        S    = fmaf(al_[j], S, be_[j]);                                        \
    }                                                                          \
    if (lane == 63) weff[((TT) - 1) * ODIM + o] = S;                           \
} while (0)

__global__ __launch_bounds__(64) void weff_tab_kernel(const float4* __restrict__ ctab,
                                                      const float* __restrict__ mlp_w,
                                                      float* __restrict__ weff) {
    const int o    = blockIdx.x;   // 0..9
    const int lane = threadIdx.x;  // 0..63

    float G[4];
#pragma unroll
    for (int j = 0; j < 4; ++j) {
        const int k = 255 - (4 * lane + j);
        G[j] = sqrtf((float)(2 * k + 1)) * mlp_w[o * NDIM + k];
    }

    // 8-deep register ring of coefficient rows (named buffers: no runtime
    // indexing -> stays in VGPRs; ~128 ring VGPRs, fine at 1 wave/SIMD)
    float4 cb0[4], cb1[4], cb2[4], cb3[4], cb4[4], cb5[4], cb6[4], cb7[4];
    {
        const float4* rp = ctab + (size_t)(T_STEPS - 1) * NDIM + 4 * lane;
#pragma unroll
        for (int j = 0; j < 4; ++j) cb0[j] = rp[j];
        rp -= NDIM;
#pragma unroll
        for (int j = 0; j < 4; ++j) cb1[j] = rp[j];
        rp -= NDIM;
#pragma unroll
        for (int j = 0; j < 4; ++j) cb2[j] = rp[j];
        rp -= NDIM;
#pragma unroll
        for (int j = 0; j < 4; ++j) cb3[j] = rp[j];
        rp -= NDIM;
#pragma unroll
        for (int j = 0; j < 4; ++j) cb4[j] = rp[j];
        rp -= NDIM;
#pragma unroll
        for (int j = 0; j < 4; ++j) cb5[j] = rp[j];
        rp -= NDIM;
#pragma unroll
        for (int j = 0; j < 4; ++j) cb6[j] = rp[j];
        rp -= NDIM;
#pragma unroll
        for (int j = 0; j < 4; ++j) cb7[j] = rp[j];
    }

    for (int t = T_STEPS; t >= 8; t -= 8) {
        WSTEP(cb0, t);
        WSTEP(cb1, t - 1);
        WSTEP(cb2, t - 2);
        WSTEP(cb3, t - 3);
        WSTEP(cb4, t - 4);
        WSTEP(cb5, t - 5);
        WSTEP(cb6, t - 6);
        WSTEP(cb7, t - 7);
    }
}

// ---------------- Weff scan kernel (inline fallback, no table) ----------------
__global__ __launch_bounds__(64) void weff_inline_kernel(const float* __restrict__ mlp_w,
                                                         float* __restrict__ weff) {
    const int o    = blockIdx.x;
    const int lane = threadIdx.x;

    float G[4], kp1[4], tk[4];
#pragma unroll
    for (int j = 0; j < 4; ++j) {
        const int k = 255 - (4 * lane + j);
        kp1[j] = (float)(k + 1);
        tk[j]  = (float)(2 * k + 1);
        G[j]   = sqrtf((float)(2 * k + 1)) * mlp_w[o * NDIM + k];
    }

    for (int t = T_STEPS; t >= 1; --t) {
        const float dt = fast_rcp((float)t);
        const float a  = 0.5f * dt;

        float d[4], a21[4], c2[4], al[4], be[4];
#pragma unroll
        for (int j = 0; j < 4; ++j) {
            const float denom = fmaf(a, kp1[j], 1.0f);
            d[j]   = fast_rcp(denom);
            a21[j] = a * tk[j];
            c2[j]  = fmaf(-a, kp1[j], 1.0f);
            al[j]  = fmaf(-a21[j], d[j], 1.0f);
            be[j]  = d[j] * G[j];
        }

        float Ac = al[0], Bc = be[0];
#pragma unroll
        for (int j = 1; j < 4; ++j) { Bc = fmaf(al[j], Bc, be[j]); Ac *= al[j]; }

        SCAN_ROUND(0x111, 0xF)
        SCAN_ROUND(0x112, 0xF)
        SCAN_ROUND(0x114, 0xF)
        SCAN_ROUND(0x118, 0xF)
        SCAN_ROUND(0x142, 0xA)
        SCAN_ROUND(0x143, 0xC)

        float S = dpp_fetch<0x138, 0xF>(Bc, 0.0f);
#pragma unroll
        for (int j = 0; j < 4; ++j) {
            const float w = a21[j] * S;
            const float u = fmaf(-d[j], w, be[j]);
            G[j] = fmaf(c2[j], u, -w);
            S    = fmaf(al[j], S, be[j]);
        }

        if (lane == 63) weff[(t - 1) * ODIM + o] = dt * S;
    }
}

// ---------------- contraction: out[b,o] = bias + sum_t f[t,b] weff[t,o] -------
__global__ __launch_bounds__(128) void partial_kernel(const float* __restrict__ f,
                                                      const float* __restrict__ weff,
                                                      float* __restrict__ part) {
    __shared__ float wsm[CHUNK * ODIM];
    const int tid = threadIdx.x;
    const int b   = blockIdx.x * 128 + tid;
    const int tc  = blockIdx.y;
    const int t0  = tc * CHUNK;

    for (int i = tid; i < CHUNK * ODIM; i += 128)
        wsm[i] = weff[t0 * ODIM + i];
    __syncthreads();

    float acc[ODIM];
#pragma unroll
    for (int o = 0; o < ODIM; ++o) acc[o] = 0.0f;

    for (int tt = 0; tt < CHUNK; ++tt) {
        const float fv = f[(t0 + tt) * BSZ + b];   // coalesced over b
#pragma unroll
        for (int o = 0; o < ODIM; ++o)
            acc[o] = fmaf(fv, wsm[tt * ODIM + o], acc[o]);
    }

#pragma unroll
    for (int o = 0; o < ODIM; ++o)
        part[(tc * BSZ + b) * ODIM + o] = acc[o];
}

__global__ __launch_bounds__(256) void reduce_kernel(const float* __restrict__ part,
                                                     const float* __restrict__ mlp_b,
                                                     float* __restrict__ out) {
    const int i = blockIdx.x * 256 + threadIdx.x;
    if (i >= BSZ * ODIM) return;
    const int o = i % ODIM;
    float s = mlp_b[o];
#pragma unroll
    for (int c = 0; c < NCHUNK; ++c) s += part[c * BSZ * ODIM + i];
    out[i] = s;
}

extern "C" void kernel_launch(void* const* d_in, const int* in_sizes, int n_in,
                              void* d_out, int out_size, void* d_ws, size_t ws_size,
                              hipStream_t stream) {
    const float* inputs = (const float*)d_in[0];  // [T=1024, B=512, 1]
    const float* mlp_w  = (const float*)d_in[1];  // [10, 256]
    const float* mlp_b  = (const float*)d_in[2];  // [10]
    float* out = (float*)d_out;                   // [512, 10]

    const size_t tab_bytes  = (size_t)T_STEPS * NDIM * sizeof(float4); // 4 MB
    const size_t weff_elems = (size_t)T_STEPS * ODIM;
    const size_t part_elems = (size_t)NCHUNK * BSZ * ODIM;
    const size_t small_bytes = (weff_elems + part_elems) * sizeof(float);

    if (ws_size >= tab_bytes + small_bytes) {
        float4* ctab = (float4*)d_ws;
        float*  weff = (float*)((char*)d_ws + tab_bytes);
        float*  part = weff + weff_elems;
        coef_kernel<<<T_STEPS, 256, 0, stream>>>(ctab);
        weff_tab_kernel<<<ODIM, 64, 0, stream>>>(ctab, mlp_w, weff);
        partial_kernel<<<dim3(BSZ / 128, NCHUNK), 128, 0, stream>>>(inputs, weff, part);
        reduce_kernel<<<(BSZ * ODIM + 255) / 256, 256, 0, stream>>>(part, mlp_b, out);
    } else {
        float* weff = (float*)d_ws;
        float* part = weff + weff_elems;
        weff_inline_kernel<<<ODIM, 64, 0, stream>>>(mlp_w, weff);
        partial_kernel<<<dim3(BSZ / 128, NCHUNK), 128, 0, stream>>>(inputs, weff, part);
        reduce_kernel<<<(BSZ * ODIM + 255) / 256, 256, 0, stream>>>(part, mlp_b, out);
    }
}

// Round 8
// 227.113 us; speedup vs baseline: 1.2119x; 1.1694x over previous
//
#include <hip/hip_runtime.h>
#include <math.h>

#define T_STEPS 1024
#define BSZ     512
#define NDIM    256
#define ODIM    10
#define NCH     4
#define CT      256      // chunk length in t: T_STEPS / NCH
#define NCHUNK  8
#define CHUNK   128      // t-chunking for the contraction kernel

// ---------------- DPP helpers (hardware-verified rounds 3/4) ----------------
template<int CTRL, int RMASK>
__device__ __forceinline__ float dpp_fetch(float x, float ident) {
    return __int_as_float(__builtin_amdgcn_update_dpp(
        __float_as_int(ident), __float_as_int(x), CTRL, RMASK, 0xF, false));
}

#define SCAN_ROUND(CTRL, RMASK)                                   \
    {   const float Ap = dpp_fetch<CTRL, RMASK>(Ac, 1.0f);        \
        const float Bp = dpp_fetch<CTRL, RMASK>(Bc, 0.0f);        \
        Bc = fmaf(Ac, Bp, Bc);                                    \
        Ac = Ac * Ap; }

// rcp + 1 Newton step (rel err ~2^-27)
__device__ __forceinline__ float fast_rcp(float x) {
    float r = __builtin_amdgcn_rcpf(x);
    return fmaf(r, fmaf(-x, r, 1.0f), r);
}

// ---------------- one backward t-step in scaled-G space ----------------
// State G_k = q_k g_k, lane l slot j holds k = 255-(4l+j) (scan order == k
// descending). Per k: S' = al*S + be ; G' = e*G - rr*S, with a = 1/(2t),
// d = 1/(1+a(k+1)), e = 2d-1, al = e + a*d, rr = 2a(2k+1)d, be = d*G.
// Returns dt*S_full (the Weff functional value; valid on lane 63).
// The map is LINEAR in G — this is what chunk-composition relies on.
__device__ __forceinline__ float wstep(float G[4], const float kp1[4],
                                       const float tk2[4], float tf) {
    const float dt = fast_rcp(tf);
    const float a  = 0.5f * dt;

    float e[4], al[4], rr[4], be[4];
#pragma unroll
    for (int j = 0; j < 4; ++j) {
        const float denom = fmaf(a, kp1[j], 1.0f);   // 1 + a(k+1)
        const float d     = fast_rcp(denom);
        const float ad    = a * d;
        e[j]  = fmaf(2.0f, d, -1.0f);                // (1 - a(k+1))d
        al[j] = e[j] + ad;                           // (1 - ak)d
        rr[j] = ad * tk2[j];                         // 2 a(2k+1) d
        be[j] = d * G[j];
    }

    float Ac = al[0], Bc = be[0];
#pragma unroll
    for (int j = 1; j < 4; ++j) { Bc = fmaf(al[j], Bc, be[j]); Ac *= al[j]; }

    SCAN_ROUND(0x111, 0xF)   // row_shr:1
    SCAN_ROUND(0x112, 0xF)   // row_shr:2
    SCAN_ROUND(0x114, 0xF)   // row_shr:4
    SCAN_ROUND(0x118, 0xF)   // row_shr:8
    SCAN_ROUND(0x142, 0xA)   // row_bcast15 -> rows 1,3
    {   // row_bcast31 -> rows 2,3 ; B-only (A unused afterwards)
        const float Bp = dpp_fetch<0x143, 0xC>(Bc, 0.0f);
        Bc = fmaf(Ac, Bp, Bc);
    }

    float S = dpp_fetch<0x138, 0xF>(Bc, 0.0f);       // excl prefix, lane0 -> 0
#pragma unroll
    for (int j = 0; j < 4; ++j) {
        G[j] = fmaf(-rr[j], S, e[j] * G[j]);
        S    = fmaf(al[j], S, be[j]);
    }
    return dt * S;                                   // lane 63: full inclusive
}

__device__ __forceinline__ void init_kmaps(int lane, float kp1[4], float tk2[4]) {
#pragma unroll
    for (int j = 0; j < 4; ++j) {
        const int k = 255 - (4 * lane + j);
        kp1[j] = (float)(k + 1);
        tk2[j] = (float)(2 * (2 * k + 1));
    }
}

// ---------------- phase 1: per-chunk basis propagation ----------------
// Wave (i, c): run chunk c's 256 steps on basis vector e_i (in G-space).
// Writes Wc[c][i][t_local] = dt*S (output functional) and P[c][i][k] = final G
// (state-transfer column i). 1024 waves total = 1 wave/SIMD chip-wide.
__global__ __launch_bounds__(64) void chunk_kernel(float* __restrict__ P,
                                                   float* __restrict__ Wc) {
    const int i    = blockIdx.x;   // basis index 0..255
    const int c    = blockIdx.y;   // chunk 0..NCH-1
    const int lane = threadIdx.x;

    float kp1[4], tk2[4], G[4];
    init_kmaps(lane, kp1, tk2);
#pragma unroll
    for (int j = 0; j < 4; ++j)
        G[j] = (4 * lane + j == 255 - i) ? 1.0f : 0.0f;   // e_i in slot layout

    float* wrow = Wc + ((size_t)(c * NDIM + i)) * CT;
    const int tend = (c + 1) * CT, tstart = c * CT;
    float tf = (float)tend;
#pragma unroll 2
    for (int t = tend; t > tstart; --t) {
        const float w = wstep(G, kp1, tk2, tf);
        if (lane == 63) wrow[t - tstart - 1] = w;
        tf -= 1.0f;
    }

    // P[c][i][k] = G at chunk left edge; slot k = 255-(4l+j) -> reversed float4
    float* prow = P + ((size_t)(c * NDIM + i)) * NDIM;
    *(float4*)(prow + (252 - 4 * lane)) = make_float4(G[3], G[2], G[1], G[0]);
}

// ---------------- phase 2: compose chunks for the 10 weight vectors ----------
// Block o: G := q .* mlp_w[o]; for c = NCH-1..0: weff rows of chunk c =
// Wc_c^T G ; state update out[k] = sum_i P[c][i][k] G[i].
__global__ __launch_bounds__(256) void compose_kernel(const float* __restrict__ mlp_w,
                                                      const float* __restrict__ P,
                                                      const float* __restrict__ Wc,
                                                      float* __restrict__ weff) {
    const int o   = blockIdx.x;    // 0..9
    const int tid = threadIdx.x;   // 0..255

    __shared__ float Gs[NDIM];
    Gs[tid] = sqrtf(2.0f * (float)tid + 1.0f) * mlp_w[o * NDIM + tid];
    __syncthreads();

    for (int c = NCH - 1; c >= 0; --c) {
        const float* Pc  = P  + (size_t)c * NDIM * NDIM;
        const float* Wcc = Wc + (size_t)c * NDIM * CT;
        float accP = 0.0f, accW = 0.0f;
#pragma unroll 4
        for (int i = 0; i < NDIM; ++i) {
            const float gi = Gs[i];
            accW = fmaf(Wcc[(size_t)i * CT + tid], gi, accW);
            accP = fmaf(Pc[(size_t)i * NDIM + tid], gi, accP);
        }
        weff[(c * CT + tid) * ODIM + o] = accW;   // t-1 = c*CT + t_local
        __syncthreads();
        Gs[tid] = accP;                            // state at next chunk's edge
        __syncthreads();
    }
}

// ---------------- fallback: single-wave sequential weff (round-5 path) -------
__global__ __launch_bounds__(64) void weff_kernel(const float* __restrict__ mlp_w,
                                                  float* __restrict__ weff) {
    const int o    = blockIdx.x;
    const int lane = threadIdx.x;

    float kp1[4], tk2[4], G[4];
    init_kmaps(lane, kp1, tk2);
#pragma unroll
    for (int j = 0; j < 4; ++j) {
        const int k = 255 - (4 * lane + j);
        G[j] = sqrtf((float)(2 * k + 1)) * mlp_w[o * NDIM + k];
    }

    float tf = (float)T_STEPS;
#pragma unroll 2
    for (int t = T_STEPS; t >= 1; --t) {
        const float w = wstep(G, kp1, tk2, tf);
        if (lane == 63) weff[(t - 1) * ODIM + o] = w;
        tf -= 1.0f;
    }
}

// ---------------- contraction: out[b,o] = bias + sum_t f[t,b] weff[t,o] ------
__global__ __launch_bounds__(128) void partial_kernel(const float* __restrict__ f,
                                                      const float* __restrict__ weff,
                                                      float* __restrict__ part) {
    __shared__ float wsm[CHUNK * ODIM];
    const int tid = threadIdx.x;
    const int b   = blockIdx.x * 128 + tid;
    const int tc  = blockIdx.y;
    const int t0  = tc * CHUNK;

    for (int i = tid; i < CHUNK * ODIM; i += 128)
        wsm[i] = weff[t0 * ODIM + i];
    __syncthreads();

    float acc[ODIM];
#pragma unroll
    for (int o = 0; o < ODIM; ++o) acc[o] = 0.0f;

    for (int tt = 0; tt < CHUNK; ++tt) {
        const float fv = f[(t0 + tt) * BSZ + b];   // coalesced over b
#pragma unroll
        for (int o = 0; o < ODIM; ++o)
            acc[o] = fmaf(fv, wsm[tt * ODIM + o], acc[o]);
    }

#pragma unroll
    for (int o = 0; o < ODIM; ++o)
        part[(tc * BSZ + b) * ODIM + o] = acc[o];
}

__global__ __launch_bounds__(256) void reduce_kernel(const float* __restrict__ part,
                                                     const float* __restrict__ mlp_b,
                                                     float* __restrict__ out) {
    const int i = blockIdx.x * 256 + threadIdx.x;
    if (i >= BSZ * ODIM) return;
    const int o = i % ODIM;
    float s = mlp_b[o];
#pragma unroll
    for (int c = 0; c < NCHUNK; ++c) s += part[c * BSZ * ODIM + i];
    out[i] = s;
}

extern "C" void kernel_launch(void* const* d_in, const int* in_sizes, int n_in,
                              void* d_out, int out_size, void* d_ws, size_t ws_size,
                              hipStream_t stream) {
    const float* inputs = (const float*)d_in[0];  // [T=1024, B=512, 1]
    const float* mlp_w  = (const float*)d_in[1];  // [10, 256]
    const float* mlp_b  = (const float*)d_in[2];  // [10]
    float* out = (float*)d_out;                   // [512, 10]

    const size_t P_elems    = (size_t)NCH * NDIM * NDIM;   // 1 MB
    const size_t Wc_elems   = (size_t)NCH * NDIM * CT;     // 1 MB
    const size_t weff_elems = (size_t)T_STEPS * ODIM;
    const size_t part_elems = (size_t)NCHUNK * BSZ * ODIM;
    const size_t need = (P_elems + Wc_elems + weff_elems + part_elems) * sizeof(float);

    if (ws_size >= need) {
        float* P    = (float*)d_ws;
        float* Wc   = P + P_elems;
        float* weff = Wc + Wc_elems;
        float* part = weff + weff_elems;
        chunk_kernel<<<dim3(NDIM, NCH), 64, 0, stream>>>(P, Wc);
        compose_kernel<<<ODIM, NDIM, 0, stream>>>(mlp_w, P, Wc, weff);
        partial_kernel<<<dim3(BSZ / 128, NCHUNK), 128, 0, stream>>>(inputs, weff, part);
        reduce_kernel<<<(BSZ * ODIM + 255) / 256, 256, 0, stream>>>(part, mlp_b, out);
    } else {
        float* weff = (float*)d_ws;
        float* part = weff + weff_elems;
        weff_kernel<<<ODIM, 64, 0, stream>>>(mlp_w, weff);
        partial_kernel<<<dim3(BSZ / 128, NCHUNK), 128, 0, stream>>>(inputs, weff, part);
        reduce_kernel<<<(BSZ * ODIM + 255) / 256, 256, 0, stream>>>(part, mlp_b, out);
    }
}

// Round 9
// 198.472 us; speedup vs baseline: 1.3868x; 1.1443x over previous
//
#include <hip/hip_runtime.h>
#include <math.h>

#define T_STEPS 1024
#define BSZ     512
#define NDIM    256
#define ODIM    10
#define NCH     8
#define CT      128      // chunk length in t: T_STEPS / NCH
#define NCHUNK  8
#define CHUNK   128      // t-chunking for the contraction kernel

// ---------------- DPP helpers (hardware-verified rounds 3/4/8) ----------------
template<int CTRL, int RMASK>
__device__ __forceinline__ float dpp_fetch(float x, float ident) {
    return __int_as_float(__builtin_amdgcn_update_dpp(
        __float_as_int(ident), __float_as_int(x), CTRL, RMASK, 0xF, false));
}

// Single-vector scan round (fallback kernel)
#define SCAN_ROUND(CTRL, RMASK)                                   \
    {   const float Ap = dpp_fetch<CTRL, RMASK>(Ac, 1.0f);        \
        const float Bp = dpp_fetch<CTRL, RMASK>(Bc, 0.0f);        \
        Bc = fmaf(Ac, Bp, Bc);                                    \
        Ac = Ac * Ap; }

// Two-vector scan round: Ac (the A-composite) is shared between both basis
// vectors since the A-coefficients are G-independent; only B duplicates.
#define SCAN2(CTRL, RMASK)                                        \
    {   const float Ap  = dpp_fetch<CTRL, RMASK>(Ac,  1.0f);      \
        const float Bp0 = dpp_fetch<CTRL, RMASK>(Bc0, 0.0f);      \
        const float Bp1 = dpp_fetch<CTRL, RMASK>(Bc1, 0.0f);      \
        Bc0 = fmaf(Ac, Bp0, Bc0);                                 \
        Bc1 = fmaf(Ac, Bp1, Bc1);                                 \
        Ac  = Ac * Ap; }

// rcp + 1 Newton step (rel err ~2^-27)
__device__ __forceinline__ float fast_rcp(float x) {
    float r = __builtin_amdgcn_rcpf(x);
    return fmaf(r, fmaf(-x, r, 1.0f), r);
}

__device__ __forceinline__ void init_kmaps(int lane, float kp1[4], float tk2[4]) {
#pragma unroll
    for (int j = 0; j < 4; ++j) {
        const int k = 255 - (4 * lane + j);
        kp1[j] = (float)(k + 1);
        tk2[j] = (float)(2 * (2 * k + 1));
    }
}

// ---------------- phase 1: per-chunk basis propagation, 2 vectors/wave --------
// Wave (bx, c): runs chunk c's CT backward steps on basis vectors e_{2bx},
// e_{2bx+1} in G-space (G_k = q_k g_k). Lane l slot j holds k = 255-(4l+j)
// (scan order == k descending). Per k: S' = al*S + be ; G' = e*G - rr*S with
// a = 1/(2t), d = 1/(1+a(k+1)), e = 2d-1, al = e+a*d, rr = 2a(2k+1)d, be = d*G.
// Coefficients and the Ac scan are shared between both vectors (V=2 ILP).
// Outputs (transposed for coalesced consumption):
//   WcT[c][tl][i] = dt*S_full   (weff functional of basis i at local step tl)
//   PT [c][k][i]  = final G_k   (chunk state-transfer)
__global__ __launch_bounds__(64, 1) void chunk_kernel(float* __restrict__ PT,
                                                      float* __restrict__ WcT) {
    const int bx   = blockIdx.x;   // basis pair 0..127
    const int c    = blockIdx.y;   // chunk 0..NCH-1
    const int lane = threadIdx.x;
    const int i0   = 2 * bx;

    float kp1[4], tk2[4], G0[4], G1[4];
    init_kmaps(lane, kp1, tk2);
#pragma unroll
    for (int j = 0; j < 4; ++j) {
        const int k = 255 - (4 * lane + j);
        G0[j] = (k == i0)     ? 1.0f : 0.0f;
        G1[j] = (k == i0 + 1) ? 1.0f : 0.0f;
    }

    float* wrow = WcT + (size_t)c * CT * NDIM + i0;
    const int tend = (c + 1) * CT, tstart = c * CT;
    float tf = (float)tend;
    for (int t = tend; t > tstart; --t) {
        const float dt = fast_rcp(tf);
        const float a  = 0.5f * dt;

        float e[4], al[4], rr[4], be0[4], be1[4];
#pragma unroll
        for (int j = 0; j < 4; ++j) {
            const float denom = fmaf(a, kp1[j], 1.0f);   // 1 + a(k+1)
            const float d     = fast_rcp(denom);
            const float ad    = a * d;
            e[j]   = fmaf(2.0f, d, -1.0f);               // (1 - a(k+1))d
            al[j]  = e[j] + ad;                          // (1 - ak)d
            rr[j]  = ad * tk2[j];                        // 2 a(2k+1) d
            be0[j] = d * G0[j];
            be1[j] = d * G1[j];
        }

        float Ac = al[0], Bc0 = be0[0], Bc1 = be1[0];
#pragma unroll
        for (int j = 1; j < 4; ++j) {
            Bc0 = fmaf(al[j], Bc0, be0[j]);
            Bc1 = fmaf(al[j], Bc1, be1[j]);
            Ac *= al[j];
        }

        SCAN2(0x111, 0xF)   // row_shr:1
        SCAN2(0x112, 0xF)   // row_shr:2
        SCAN2(0x114, 0xF)   // row_shr:4
        SCAN2(0x118, 0xF)   // row_shr:8
        SCAN2(0x142, 0xA)   // row_bcast15 -> rows 1,3
        {   // row_bcast31 -> rows 2,3 ; B-only (A unused afterwards)
            const float Bp0 = dpp_fetch<0x143, 0xC>(Bc0, 0.0f);
            const float Bp1 = dpp_fetch<0x143, 0xC>(Bc1, 0.0f);
            Bc0 = fmaf(Ac, Bp0, Bc0);
            Bc1 = fmaf(Ac, Bp1, Bc1);
        }

        float S0 = dpp_fetch<0x138, 0xF>(Bc0, 0.0f);     // excl prefix (wave_shr:1)
        float S1 = dpp_fetch<0x138, 0xF>(Bc1, 0.0f);
#pragma unroll
        for (int j = 0; j < 4; ++j) {
            G0[j] = fmaf(-rr[j], S0, e[j] * G0[j]);
            G1[j] = fmaf(-rr[j], S1, e[j] * G1[j]);
            S0 = fmaf(al[j], S0, be0[j]);
            S1 = fmaf(al[j], S1, be1[j]);
        }

        if (lane == 63)
            *(float2*)(wrow + (size_t)(t - tstart - 1) * NDIM) =
                make_float2(dt * S0, dt * S1);
        tf -= 1.0f;
    }

    // PT[c][k][i0..i0+1] = final G (state entering chunk from the left)
#pragma unroll
    for (int j = 0; j < 4; ++j) {
        const int k = 255 - (4 * lane + j);
        *(float2*)(PT + ((size_t)c * NDIM + k) * NDIM + i0) =
            make_float2(G0[j], G1[j]);
    }
}

// ---------------- phase 2a: sequential edge-state propagation ----------------
// Block o: Gs = q .* mlp_w[o]; for c = NCH-1..0: R[c][o][:] = Gs (state
// entering chunk c from the right); then Gs[k] = sum_i PT[c][k][i] Gs[i].
__global__ __launch_bounds__(256) void r_kernel(const float* __restrict__ mlp_w,
                                                const float* __restrict__ PT,
                                                float* __restrict__ R) {
    const int o   = blockIdx.x;    // 0..9
    const int tid = threadIdx.x;   // 0..255

    __shared__ float Gs[NDIM];
    Gs[tid] = sqrtf(2.0f * (float)tid + 1.0f) * mlp_w[o * NDIM + tid];
    __syncthreads();

    for (int c = NCH - 1; c >= 0; --c) {
        R[((size_t)c * ODIM + o) * NDIM + tid] = Gs[tid];
        if (c > 0) {
            const float4* row = (const float4*)(PT + ((size_t)c * NDIM + tid) * NDIM);
            float a0 = 0.f, a1 = 0.f, a2 = 0.f, a3 = 0.f;
#pragma unroll 8
            for (int ii = 0; ii < NDIM / 4; ++ii) {
                const float4 r4 = row[ii];
                a0 = fmaf(r4.x, Gs[4 * ii + 0], a0);
                a1 = fmaf(r4.y, Gs[4 * ii + 1], a1);
                a2 = fmaf(r4.z, Gs[4 * ii + 2], a2);
                a3 = fmaf(r4.w, Gs[4 * ii + 3], a3);
            }
            const float y = (a0 + a1) + (a2 + a3);
            __syncthreads();
            Gs[tid] = y;
            __syncthreads();
        }
    }
}

// ---------------- phase 2b: parallel weff emission ----------------
// weff[r][o] = dot(WcT[r][:], R[c(r)][o][:]), r = t-1 = 0..1023.
// One wave per r (4 waves/block; all 4 rows in the same chunk since 4 | CT).
__global__ __launch_bounds__(256) void z_kernel(const float* __restrict__ WcT,
                                                const float* __restrict__ R,
                                                float* __restrict__ weff) {
    __shared__ float Rl[ODIM * NDIM];
    const int tid = threadIdx.x;
    const int r0  = blockIdx.x * 4;
    const int c   = r0 / CT;

    for (int idx = tid; idx < ODIM * NDIM; idx += 256)
        Rl[idx] = R[(size_t)c * ODIM * NDIM + idx];
    __syncthreads();

    const int w    = tid >> 6;
    const int lane = tid & 63;
    const int r    = r0 + w;
    const float4 w4 = *(const float4*)(WcT + (size_t)r * NDIM + 4 * lane);

#pragma unroll
    for (int o = 0; o < ODIM; ++o) {
        const float* Ro = Rl + o * NDIM + 4 * lane;
        float p = fmaf(w4.x, Ro[0], fmaf(w4.y, Ro[1],
                  fmaf(w4.z, Ro[2], w4.w * Ro[3])));
#pragma unroll
        for (int m = 1; m < 64; m <<= 1) p += __shfl_xor(p, m);
        if (lane == o) weff[(size_t)r * ODIM + o] = p;
    }
}

// ---------------- fallback: single-wave sequential weff (r8-verified) --------
__device__ __forceinline__ float wstep(float G[4], const float kp1[4],
                                       const float tk2[4], float tf) {
    const float dt = fast_rcp(tf);
    const float a  = 0.5f * dt;

    float e[4], al[4], rr[4], be[4];
#pragma unroll
    for (int j = 0; j < 4; ++j) {
        const float denom = fmaf(a, kp1[j], 1.0f);
        const float d     = fast_rcp(denom);
        const float ad    = a * d;
        e[j]  = fmaf(2.0f, d, -1.0f);
        al[j] = e[j] + ad;
        rr[j] = ad * tk2[j];
        be[j] = d * G[j];
    }

    float Ac = al[0], Bc = be[0];
#pragma unroll
    for (int j = 1; j < 4; ++j) { Bc = fmaf(al[j], Bc, be[j]); Ac *= al[j]; }

    SCAN_ROUND(0x111, 0xF)
    SCAN_ROUND(0x112, 0xF)
    SCAN_ROUND(0x114, 0xF)
    SCAN_ROUND(0x118, 0xF)
    SCAN_ROUND(0x142, 0xA)
    {
        const float Bp = dpp_fetch<0x143, 0xC>(Bc, 0.0f);
        Bc = fmaf(Ac, Bp, Bc);
    }

    float S = dpp_fetch<0x138, 0xF>(Bc, 0.0f);
#pragma unroll
    for (int j = 0; j < 4; ++j) {
        G[j] = fmaf(-rr[j], S, e[j] * G[j]);
        S    = fmaf(al[j], S, be[j]);
    }
    return dt * S;
}

__global__ __launch_bounds__(64) void weff_kernel(const float* __restrict__ mlp_w,
                                                  float* __restrict__ weff) {
    const int o    = blockIdx.x;
    const int lane = threadIdx.x;

    float kp1[4], tk2[4], G[4];
    init_kmaps(lane, kp1, tk2);
#pragma unroll
    for (int j = 0; j < 4; ++j) {
        const int k = 255 - (4 * lane + j);
        G[j] = sqrtf((float)(2 * k + 1)) * mlp_w[o * NDIM + k];
    }

    float tf = (float)T_STEPS;
#pragma unroll 2
    for (int t = T_STEPS; t >= 1; --t) {
        const float w = wstep(G, kp1, tk2, tf);
        if (lane == 63) weff[(t - 1) * ODIM + o] = w;
        tf -= 1.0f;
    }
}

// ---------------- contraction: out[b,o] = bias + sum_t f[t,b] weff[t,o] ------
__global__ __launch_bounds__(128) void partial_kernel(const float* __restrict__ f,
                                                      const float* __restrict__ weff,
                                                      float* __restrict__ part) {
    __shared__ float wsm[CHUNK * ODIM];
    const int tid = threadIdx.x;
    const int b   = blockIdx.x * 128 + tid;
    const int tc  = blockIdx.y;
    const int t0  = tc * CHUNK;

    for (int i = tid; i < CHUNK * ODIM; i += 128)
        wsm[i] = weff[t0 * ODIM + i];
    __syncthreads();

    float acc[ODIM];
#pragma unroll
    for (int o = 0; o < ODIM; ++o) acc[o] = 0.0f;

    for (int tt = 0; tt < CHUNK; ++tt) {
        const float fv = f[(t0 + tt) * BSZ + b];   // coalesced over b
#pragma unroll
        for (int o = 0; o < ODIM; ++o)
            acc[o] = fmaf(fv, wsm[tt * ODIM + o], acc[o]);
    }

#pragma unroll
    for (int o = 0; o < ODIM; ++o)
        part[(tc * BSZ + b) * ODIM + o] = acc[o];
}

__global__ __launch_bounds__(256) void reduce_kernel(const float* __restrict__ part,
                                                     const float* __restrict__ mlp_b,
                                                     float* __restrict__ out) {
    const int i = blockIdx.x * 256 + threadIdx.x;
    if (i >= BSZ * ODIM) return;
    const int o = i % ODIM;
    float s = mlp_b[o];
#pragma unroll
    for (int c = 0; c < NCHUNK; ++c) s += part[c * BSZ * ODIM + i];
    out[i] = s;
}

extern "C" void kernel_launch(void* const* d_in, const int* in_sizes, int n_in,
                              void* d_out, int out_size, void* d_ws, size_t ws_size,
                              hipStream_t stream) {
    const float* inputs = (const float*)d_in[0];  // [T=1024, B=512, 1]
    const float* mlp_w  = (const float*)d_in[1];  // [10, 256]
    const float* mlp_b  = (const float*)d_in[2];  // [10]
    float* out = (float*)d_out;                   // [512, 10]

    const size_t PT_elems   = (size_t)NCH * NDIM * NDIM;   // 2 MB
    const size_t WcT_elems  = (size_t)NCH * CT * NDIM;     // 1 MB
    const size_t R_elems    = (size_t)NCH * ODIM * NDIM;   // 80 KB
    const size_t weff_elems = (size_t)T_STEPS * ODIM;
    const size_t part_elems = (size_t)NCHUNK * BSZ * ODIM;
    const size_t need = (PT_elems + WcT_elems + R_elems + weff_elems + part_elems)
                        * sizeof(float);

    if (ws_size >= need) {
        float* PT   = (float*)d_ws;
        float* WcT  = PT + PT_elems;
        float* R    = WcT + WcT_elems;
        float* weff = R + R_elems;
        float* part = weff + weff_elems;
        chunk_kernel<<<dim3(NDIM / 2, NCH), 64, 0, stream>>>(PT, WcT);
        r_kernel<<<ODIM, NDIM, 0, stream>>>(mlp_w, PT, R);
        z_kernel<<<T_STEPS / 4, 256, 0, stream>>>(WcT, R, weff);
        partial_kernel<<<dim3(BSZ / 128, NCHUNK), 128, 0, stream>>>(inputs, weff, part);
        reduce_kernel<<<(BSZ * ODIM + 255) / 256, 256, 0, stream>>>(part, mlp_b, out);
    } else {
        float* weff = (float*)d_ws;
        float* part = weff + weff_elems;
        weff_kernel<<<ODIM, 64, 0, stream>>>(mlp_w, weff);
        partial_kernel<<<dim3(BSZ / 128, NCHUNK), 128, 0, stream>>>(inputs, weff, part);
        reduce_kernel<<<(BSZ * ODIM + 255) / 256, 256, 0, stream>>>(part, mlp_b, out);
    }
}